// Round 1
// baseline (248.899 us; speedup 1.0000x reference)
//
#include <hip/hip_runtime.h>

#define Bn   8
#define Cn   64
#define Hn   128
#define Wn   128
#define KK   9
#define OffC 18
#define NG   4
#define Cg   16
#define HW   (Hn*Wn)

// ---------------- Kernel 1: offset conv (3x3, 64 -> 18, pad 1) ----------------
// grid: Bn*Hn/4 blocks, 256 threads. Each block: 4 rows of one batch.
// Each thread: 2 pixels (wo, wo+64) in one row, all 18 output channels.
__global__ __launch_bounds__(256) void offset_conv_kernel(
    const float* __restrict__ x, const float* __restrict__ w,
    const float* __restrict__ bias, float* __restrict__ offs)
{
    __shared__ float wl[OffC * Cn * KK];   // 10368 floats = 41.5 KB
    __shared__ float bl[OffC];
    const int tid = threadIdx.x;
    for (int i = tid; i < OffC * Cn * KK; i += 256) wl[i] = w[i];
    if (tid < OffC) bl[tid] = bias[tid];
    __syncthreads();

    const int rb  = blockIdx.x % (Hn / 4);
    const int b   = blockIdx.x / (Hn / 4);
    const int row = tid >> 6;       // 0..3
    const int wo0 = tid & 63;       // 0..63 ; second pixel at wo0+64
    const int ho  = rb * 4 + row;

    float acc0[OffC], acc1[OffC];
#pragma unroll
    for (int o = 0; o < OffC; o++) { acc0[o] = bl[o]; acc1[o] = bl[o]; }

    const float* xb = x + b * Cn * HW;
    for (int ci = 0; ci < Cn; ci++) {
        const float* xc = xb + ci * HW;
#pragma unroll
        for (int ky = 0; ky < 3; ky++) {
            const int y = ho - 1 + ky;
            const bool yok = ((unsigned)y < (unsigned)Hn);
            const float* xr = xc + y * Wn;
#pragma unroll
            for (int kx = 0; kx < 3; kx++) {
                const int xa = wo0 - 1 + kx;
                const int xb2 = wo0 + 64 - 1 + kx;
                const float v0 = (yok && (unsigned)xa  < (unsigned)Wn) ? xr[xa]  : 0.f;
                const float v1 = (yok && (unsigned)xb2 < (unsigned)Wn) ? xr[xb2] : 0.f;
                const int wbase = ci * KK + ky * 3 + kx;
#pragma unroll
                for (int o = 0; o < OffC; o++) {
                    const float wv = wl[o * (Cn * KK) + wbase];
                    acc0[o] += v0 * wv;
                    acc1[o] += v1 * wv;
                }
            }
        }
    }

    float* ob = offs + ((size_t)b * OffC * Hn + ho) * Wn;
#pragma unroll
    for (int o = 0; o < OffC; o++) {
        ob[o * HW + wo0]      = acc0[o];
        ob[o * HW + wo0 + 64] = acc1[o];
    }
}

// ---------------- Kernel 2: grouped deformable conv ----------------
// grid: (Hn/2, Bn*NG), 128 threads. Thread: one column wo, rows ho0, ho0+1,
// all 16 output channels of group g.
__global__ __launch_bounds__(128) void deform_kernel(
    const float* __restrict__ skip, const float* __restrict__ offs,
    const float* __restrict__ dw, float* __restrict__ out)
{
    __shared__ float wl[Cg * Cg * KK];   // 2304 floats (group slice, contiguous)
    const int tid = threadIdx.x;
    const int g = blockIdx.y & 3;
    const int b = blockIdx.y >> 2;
    for (int i = tid; i < Cg * Cg * KK; i += 128) wl[i] = dw[g * Cg * Cg * KK + i];
    __syncthreads();

    const int wo  = tid;            // 0..127
    const int ho0 = blockIdx.x * 2;

    float acc[2][Cg];
#pragma unroll
    for (int p = 0; p < 2; p++)
#pragma unroll
        for (int o = 0; o < Cg; o++) acc[p][o] = 0.f;

    const float* sg   = skip + ((size_t)b * Cn + g * Cg) * HW;
    const float* offb = offs + (size_t)b * OffC * HW;

    for (int k = 0; k < KK; k++) {
        const int ky = k / 3, kx = k % 3;
        int   i00[2], i01[2], i10[2], i11[2];
        float m00[2], m01[2], m10[2], m11[2];
#pragma unroll
        for (int p = 0; p < 2; p++) {
            const int ho = ho0 + p;
            const float offy = offb[((2 * k)     * Hn + ho) * Wn + wo];
            const float offx = offb[((2 * k + 1) * Hn + ho) * Wn + wo];
            const float py = (float)(ho - 1 + ky) + offy;
            const float px = (float)(wo - 1 + kx) + offx;
            const float y0f = floorf(py), x0f = floorf(px);
            const float wy = py - y0f, wx = px - x0f;
            const int y0 = (int)y0f, x0 = (int)x0f;
            const int y1 = y0 + 1,  x1 = x0 + 1;
            const bool vy0 = ((unsigned)y0 < (unsigned)Hn);
            const bool vy1 = ((unsigned)y1 < (unsigned)Hn);
            const bool vx0 = ((unsigned)x0 < (unsigned)Wn);
            const bool vx1 = ((unsigned)x1 < (unsigned)Wn);
            const int y0c = min(max(y0, 0), Hn - 1);
            const int y1c = min(max(y1, 0), Hn - 1);
            const int x0c = min(max(x0, 0), Wn - 1);
            const int x1c = min(max(x1, 0), Wn - 1);
            // fold validity into bilerp weights -> unconditional clamped loads
            m00[p] = (1.f - wy) * (1.f - wx) * (vy0 && vx0 ? 1.f : 0.f);
            m01[p] = (1.f - wy) * wx         * (vy0 && vx1 ? 1.f : 0.f);
            m10[p] = wy * (1.f - wx)         * (vy1 && vx0 ? 1.f : 0.f);
            m11[p] = wy * wx                 * (vy1 && vx1 ? 1.f : 0.f);
            i00[p] = y0c * Wn + x0c;
            i01[p] = y0c * Wn + x1c;
            i10[p] = y1c * Wn + x0c;
            i11[p] = y1c * Wn + x1c;
        }
#pragma unroll
        for (int c = 0; c < Cg; c++) {
            const float* sc = sg + c * HW;
            const float s0 = sc[i00[0]] * m00[0] + sc[i01[0]] * m01[0]
                           + sc[i10[0]] * m10[0] + sc[i11[0]] * m11[0];
            const float s1 = sc[i00[1]] * m00[1] + sc[i01[1]] * m01[1]
                           + sc[i10[1]] * m10[1] + sc[i11[1]] * m11[1];
#pragma unroll
            for (int o = 0; o < Cg; o++) {
                const float wv = wl[o * (Cg * KK) + c * KK + k];
                acc[0][o] += s0 * wv;
                acc[1][o] += s1 * wv;
            }
        }
    }

#pragma unroll
    for (int p = 0; p < 2; p++) {
        float* ob = out + (((size_t)b * Cn + g * Cg) * Hn + (ho0 + p)) * Wn + wo;
#pragma unroll
        for (int o = 0; o < Cg; o++) ob[o * HW] = acc[p][o];
    }
}

extern "C" void kernel_launch(void* const* d_in, const int* in_sizes, int n_in,
                              void* d_out, int out_size, void* d_ws, size_t ws_size,
                              hipStream_t stream) {
    const float* x        = (const float*)d_in[0];
    const float* skip     = (const float*)d_in[1];
    const float* offset_w = (const float*)d_in[2];
    const float* offset_b = (const float*)d_in[3];
    const float* deform_w = (const float*)d_in[4];
    float* out  = (float*)d_out;
    float* offs = (float*)d_ws;   // Bn*OffC*Hn*Wn floats = 9.4 MB

    hipLaunchKernelGGL(offset_conv_kernel, dim3(Bn * Hn / 4), dim3(256), 0, stream,
                       x, offset_w, offset_b, offs);
    hipLaunchKernelGGL(deform_kernel, dim3(Hn / 2, Bn * NG), dim3(128), 0, stream,
                       skip, offs, deform_w, out);
}